// Round 1
// baseline (3382.241 us; speedup 1.0000x reference)
//
#include <hip/hip_runtime.h>
#include <math.h>

#define Bsz 8
#define Sq  1024
#define Hd  768
#define NHd 12
#define DHd 64

// ---------------- generic tiled fp32 GEMM: C = A[M,K] @ W[K,N] + bias, opt ReLU ----------------
template<bool RELU>
__global__ __launch_bounds__(256) void gemm_bias(const float* __restrict__ A,
                                                 const float* __restrict__ W,
                                                 const float* __restrict__ bias,
                                                 float* __restrict__ C,
                                                 int M, int N, int K) {
    const int bm = blockIdx.y * 64;
    const int bn = blockIdx.x * 64;
    const int t  = threadIdx.x;
    const int tx = t & 15;
    const int ty = t >> 4;
    __shared__ float Ast[16][68];   // [k][m], padded
    __shared__ float Wsm[16][68];   // [k][n], padded
    float acc[4][4] = {};
    const int mA  = t >> 2;
    const int kvA = (t & 3) * 4;
    const int kW  = t >> 4;
    const int nW  = (t & 15) * 4;
    for (int k0 = 0; k0 < K; k0 += 16) {
        float4 a4 = *(const float4*)(A + (size_t)(bm + mA) * K + (k0 + kvA));
        float4 w4 = *(const float4*)(W + (size_t)(k0 + kW) * N + (bn + nW));
        Ast[kvA + 0][mA] = a4.x;
        Ast[kvA + 1][mA] = a4.y;
        Ast[kvA + 2][mA] = a4.z;
        Ast[kvA + 3][mA] = a4.w;
        *(float4*)(&Wsm[kW][nW]) = w4;
        __syncthreads();
#pragma unroll
        for (int kk = 0; kk < 16; ++kk) {
            float4 av = *(const float4*)(&Ast[kk][ty * 4]);
            float4 bv = *(const float4*)(&Wsm[kk][tx * 4]);
            float aa[4] = {av.x, av.y, av.z, av.w};
            float bb[4] = {bv.x, bv.y, bv.z, bv.w};
#pragma unroll
            for (int i = 0; i < 4; ++i)
#pragma unroll
                for (int j = 0; j < 4; ++j)
                    acc[i][j] = fmaf(aa[i], bb[j], acc[i][j]);
        }
        __syncthreads();
    }
#pragma unroll
    for (int i = 0; i < 4; ++i) {
        const int m = bm + ty * 4 + i;
#pragma unroll
        for (int j = 0; j < 4; ++j) {
            const int n = bn + tx * 4 + j;
            float v = acc[i][j] + bias[n];
            if (RELU) v = fmaxf(v, 0.0f);
            C[(size_t)m * N + n] = v;
        }
    }
}

// ---------------- attention: one block per (b, h, 8-query tile) ----------------
// scores = QK^T/8 ; p = softmax(scores) ; p *= mask ; ctx = p @ V
// denom is over UNMASKED probs (mask applied post-softmax, no renorm) — matches reference.
__global__ __launch_bounds__(256) void attn_kernel(const float* __restrict__ qm,
                                                   const float* __restrict__ km,
                                                   const float* __restrict__ vm,
                                                   const float* __restrict__ mask,
                                                   float* __restrict__ ctx) {
    const int QT  = 8;
    const int nqt = Sq / QT;                    // 128
    const int bh  = blockIdx.x / nqt;
    const int qt  = blockIdx.x % nqt;
    const int b   = bh / NHd;
    const int h   = bh % NHd;
    const int t   = threadIdx.x;

    __shared__ float q_s[QT][DHd];              // 2 KB
    __shared__ float sc[QT][Sq];                // 32 KB
    __shared__ float red[4][QT][DHd];           // 8 KB
    __shared__ float inv_den[QT];

    const size_t rowbase = (size_t)b * Sq;      // row index base in [B*S, H] activations

    // load Q tile
    for (int i = t; i < QT * DHd; i += 256) {
        const int r = i / DHd, d = i % DHd;
        q_s[r][d] = qm[(rowbase + qt * QT + r) * Hd + h * DHd + d];
    }
    __syncthreads();

    // stage 1: scores — thread t handles k = c*256 + t
#pragma unroll 1
    for (int c = 0; c < 4; ++c) {
        const int k = c * 256 + t;
        const float* Krow = km + (rowbase + k) * Hd + h * DHd;
        float accr[QT] = {};
        for (int d4 = 0; d4 < DHd; d4 += 4) {
            const float4 k4 = *(const float4*)(Krow + d4);
#pragma unroll
            for (int r = 0; r < QT; ++r) {
                const float4 q4 = *(const float4*)(&q_s[r][d4]);
                accr[r] += k4.x * q4.x + k4.y * q4.y + k4.z * q4.z + k4.w * q4.w;
            }
        }
#pragma unroll
        for (int r = 0; r < QT; ++r) sc[r][k] = accr[r] * 0.125f;
    }
    __syncthreads();

    // stage 2: per-row softmax (32 lanes per row), fold mask in, store p*mask
    {
        const int r = t >> 5;
        const int l = t & 31;
        float mx = -INFINITY;
        for (int k = l; k < Sq; k += 32) mx = fmaxf(mx, sc[r][k]);
#pragma unroll
        for (int off = 16; off > 0; off >>= 1) mx = fmaxf(mx, __shfl_xor(mx, off));
        float sum = 0.0f;
        for (int k = l; k < Sq; k += 32) sum += __expf(sc[r][k] - mx);
#pragma unroll
        for (int off = 16; off > 0; off >>= 1) sum += __shfl_xor(sum, off);
        const float* mrow = mask + ((size_t)b * Sq + (qt * QT + r)) * Sq;
        for (int k = l; k < Sq; k += 32) sc[r][k] = __expf(sc[r][k] - mx) * mrow[k];
        if (l == 0) inv_den[r] = 1.0f / sum;
    }
    __syncthreads();

    // stage 3: ctx = (p*mask) @ V / denom — 4 groups of 64 lanes, lane = d
    {
        const int g = t >> 6;
        const int d = t & 63;
        float part[QT] = {};
        const float* Vbase = vm + rowbase * Hd + h * DHd + d;
        for (int k = g * 256; k < g * 256 + 256; ++k) {
            const float v = Vbase[(size_t)k * Hd];
#pragma unroll
            for (int r = 0; r < QT; ++r) part[r] = fmaf(sc[r][k], v, part[r]);
        }
#pragma unroll
        for (int r = 0; r < QT; ++r) red[g][r][d] = part[r];
    }
    __syncthreads();
    for (int i = t; i < QT * DHd; i += 256) {
        const int r = i / DHd, d = i % DHd;
        const float v = (red[0][r][d] + red[1][r][d] + red[2][r][d] + red[3][r][d]) * inv_den[r];
        ctx[(rowbase + qt * QT + r) * Hd + h * DHd + d] = v;
    }
}

// ---------------- fused residual + layernorm: out = LN(a + b)*g + be ----------------
__global__ __launch_bounds__(256) void ln_kernel(const float* __restrict__ a,
                                                 const float* __restrict__ bres,
                                                 const float* __restrict__ g,
                                                 const float* __restrict__ be,
                                                 float* __restrict__ out) {
    const int row = blockIdx.x;
    const int t   = threadIdx.x;
    const float* pa = a + (size_t)row * Hd;
    const float* pb = bres + (size_t)row * Hd;
    __shared__ float red[4];
    float v[3];
#pragma unroll
    for (int i = 0; i < 3; ++i) v[i] = pa[t + i * 256] + pb[t + i * 256];

    float s = v[0] + v[1] + v[2];
#pragma unroll
    for (int off = 32; off > 0; off >>= 1) s += __shfl_xor(s, off);
    if ((t & 63) == 0) red[t >> 6] = s;
    __syncthreads();
    const float mu = (red[0] + red[1] + red[2] + red[3]) * (1.0f / Hd);
    __syncthreads();

    float sq = 0.0f;
#pragma unroll
    for (int i = 0; i < 3; ++i) {
        v[i] -= mu;
        sq = fmaf(v[i], v[i], sq);
    }
#pragma unroll
    for (int off = 32; off > 0; off >>= 1) sq += __shfl_xor(sq, off);
    if ((t & 63) == 0) red[t >> 6] = sq;
    __syncthreads();
    const float var = (red[0] + red[1] + red[2] + red[3]) * (1.0f / Hd);
    const float rs  = rsqrtf(var + 1e-5f);
#pragma unroll
    for (int i = 0; i < 3; ++i) {
        const int idx = t + i * 256;
        out[(size_t)row * Hd + idx] = v[i] * rs * g[idx] + be[idx];
    }
}

extern "C" void kernel_launch(void* const* d_in, const int* in_sizes, int n_in,
                              void* d_out, int out_size, void* d_ws, size_t ws_size,
                              hipStream_t stream) {
    const float* x1    = (const float*)d_in[0];
    const float* wmask = (const float*)d_in[1];
    const float* Wq    = (const float*)d_in[2];
    const float* bq    = (const float*)d_in[3];
    const float* Wk    = (const float*)d_in[4];
    const float* bk    = (const float*)d_in[5];
    const float* Wv    = (const float*)d_in[6];
    const float* bv    = (const float*)d_in[7];
    const float* g1    = (const float*)d_in[8];
    const float* be1   = (const float*)d_in[9];
    const float* g2    = (const float*)d_in[10];
    const float* be2   = (const float*)d_in[11];
    const float* W1    = (const float*)d_in[12];
    const float* b1    = (const float*)d_in[13];
    const float* W2    = (const float*)d_in[14];
    const float* b2    = (const float*)d_in[15];
    float* out = (float*)d_out;
    float* ws  = (float*)d_ws;

    const size_t NT = (size_t)Bsz * Sq * Hd;    // 6291456
    float* qm   = ws;                           // [8192,768]
    float* km   = ws + NT;
    float* vm   = ws + 2 * NT;
    float* ctx  = ws + 3 * NT;
    float* hb   = ws + 4 * NT;                  // [8192,1536]
    float* xb   = km;                           // reuse after attention
    float* ffb  = vm;                           // reuse after attention

    const int M = Bsz * Sq;                     // 8192
    dim3 blk(256);

    gemm_bias<false><<<dim3(Hd / 64, M / 64), blk, 0, stream>>>(x1, Wq, bq, qm, M, Hd, Hd);
    gemm_bias<false><<<dim3(Hd / 64, M / 64), blk, 0, stream>>>(x1, Wk, bk, km, M, Hd, Hd);
    gemm_bias<false><<<dim3(Hd / 64, M / 64), blk, 0, stream>>>(x1, Wv, bv, vm, M, Hd, Hd);

    attn_kernel<<<dim3(Bsz * NHd * (Sq / 8)), blk, 0, stream>>>(qm, km, vm, wmask, ctx);

    ln_kernel<<<dim3(M), blk, 0, stream>>>(ctx, qm, g1, be1, xb);

    gemm_bias<true ><<<dim3((2 * Hd) / 64, M / 64), blk, 0, stream>>>(xb, W1, b1, hb, M, 2 * Hd, Hd);
    gemm_bias<false><<<dim3(Hd / 64, M / 64), blk, 0, stream>>>(hb, W2, b2, ffb, M, Hd, 2 * Hd);

    ln_kernel<<<dim3(M), blk, 0, stream>>>(xb, ffb, g2, be2, out);
}

// Round 2
// 1248.359 us; speedup vs baseline: 2.7094x; 2.7094x over previous
//
#include <hip/hip_runtime.h>
#include <math.h>

#define Bsz 8
#define Sq  1024
#define Hd  768
#define NHd 12
#define DHd 64

typedef __attribute__((ext_vector_type(8))) short bf16x8;
typedef __attribute__((ext_vector_type(4))) float f32x4;

__device__ __forceinline__ ushort f2bf(float f) {
    unsigned u = __float_as_uint(f);
    u += 0x7fffu + ((u >> 16) & 1u);     // RNE
    return (ushort)(u >> 16);
}

// ---------------- fp32 -> bf16 conversion (4 elems/thread) ----------------
__global__ __launch_bounds__(256) void cvt_bf16(const float* __restrict__ a,
                                                ushort* __restrict__ o, int n4) {
    int i = blockIdx.x * 256 + threadIdx.x;
    if (i < n4) {
        float4 f = ((const float4*)a)[i];
        ushort4 u;
        u.x = f2bf(f.x); u.y = f2bf(f.y); u.z = f2bf(f.z); u.w = f2bf(f.w);
        ((ushort4*)o)[i] = u;
    }
}

// ---------------- generic tiled fp32 GEMM: C = A[M,K] @ W[K,N] + bias, opt ReLU ----------------
template<bool RELU>
__global__ __launch_bounds__(256) void gemm_bias(const float* __restrict__ A,
                                                 const float* __restrict__ W,
                                                 const float* __restrict__ bias,
                                                 float* __restrict__ C,
                                                 int M, int N, int K) {
    const int bm = blockIdx.y * 64;
    const int bn = blockIdx.x * 64;
    const int t  = threadIdx.x;
    const int tx = t & 15;
    const int ty = t >> 4;
    __shared__ float Ast[16][68];   // [k][m], padded
    __shared__ float Wsm[16][68];   // [k][n], padded
    float acc[4][4] = {};
    const int mA  = t >> 2;
    const int kvA = (t & 3) * 4;
    const int kW  = t >> 4;
    const int nW  = (t & 15) * 4;
    for (int k0 = 0; k0 < K; k0 += 16) {
        float4 a4 = *(const float4*)(A + (size_t)(bm + mA) * K + (k0 + kvA));
        float4 w4 = *(const float4*)(W + (size_t)(k0 + kW) * N + (bn + nW));
        Ast[kvA + 0][mA] = a4.x;
        Ast[kvA + 1][mA] = a4.y;
        Ast[kvA + 2][mA] = a4.z;
        Ast[kvA + 3][mA] = a4.w;
        *(float4*)(&Wsm[kW][nW]) = w4;
        __syncthreads();
#pragma unroll
        for (int kk = 0; kk < 16; ++kk) {
            float4 av = *(const float4*)(&Ast[kk][ty * 4]);
            float4 bv = *(const float4*)(&Wsm[kk][tx * 4]);
            float aa[4] = {av.x, av.y, av.z, av.w};
            float bb[4] = {bv.x, bv.y, bv.z, bv.w};
#pragma unroll
            for (int i = 0; i < 4; ++i)
#pragma unroll
                for (int j = 0; j < 4; ++j)
                    acc[i][j] = fmaf(aa[i], bb[j], acc[i][j]);
        }
        __syncthreads();
    }
#pragma unroll
    for (int i = 0; i < 4; ++i) {
        const int m = bm + ty * 4 + i;
#pragma unroll
        for (int j = 0; j < 4; ++j) {
            const int n = bn + tx * 4 + j;
            float v = acc[i][j] + bias[n];
            if (RELU) v = fmaxf(v, 0.0f);
            C[(size_t)m * N + n] = v;
        }
    }
}

// ---------------- MFMA flash attention ----------------
// Block = (b, h, 64-query tile), 256 threads = 4 waves, each wave owns 16 q rows.
// Online softmax; denominator over UNMASKED exp (mask applied post-softmax to P only).
// Layouts (gfx950 mfma_f32_16x16x32_bf16): A[m=lane&15][k=quad*8+j],
// B[k=quad*8+j][n=lane&15], C/D[row=quad*4+reg][col=lane&15].
__global__ __launch_bounds__(256) void attn_mfma(const ushort* __restrict__ qb,
                                                 const ushort* __restrict__ kb,
                                                 const ushort* __restrict__ vb,
                                                 const float* __restrict__ mask,
                                                 float* __restrict__ ctx) {
    const int nqt  = Sq / 64;                 // 16
    const int bh   = blockIdx.x / nqt;
    const int qt   = blockIdx.x % nqt;
    const int b    = bh / NHd;
    const int h    = bh % NHd;
    const int t    = threadIdx.x;
    const int wave = t >> 6;
    const int lane = t & 63;
    const int l15  = lane & 15;
    const int quad = lane >> 4;

    __shared__ ushort Qs[64][72];             // q rows, padded stride 72
    __shared__ ushort Ks[64][72];             // key rows
    __shared__ ushort Vt[DHd][72];            // V transposed: [d][key]
    __shared__ ushort Pt[4][16][72];          // per-wave P (A-layout staging)

    const size_t rowbase = (size_t)b * Sq;
    const size_t colbase = (size_t)h * DHd;

    // stage Q tile (bf16) into LDS: thread t -> row t>>2, 16 elems at col (t&3)*16
    {
        const int r = t >> 2, c = (t & 3) * 16;
        const ushort* src = qb + (rowbase + qt * 64 + r) * Hd + colbase + c;
        *(int4*)&Qs[r][c]     = *(const int4*)(src);
        *(int4*)&Qs[r][c + 8] = *(const int4*)(src + 8);
    }
    __syncthreads();

    // Q A-fragments (constant over K loop)
    bf16x8 qf0 = *(const bf16x8*)&Qs[wave * 16 + l15][quad * 8];
    bf16x8 qf1 = *(const bf16x8*)&Qs[wave * 16 + l15][32 + quad * 8];

    f32x4 o[4] = {{0,0,0,0},{0,0,0,0},{0,0,0,0},{0,0,0,0}};
    float m_i[4] = {-INFINITY, -INFINITY, -INFINITY, -INFINITY};
    float l_i[4] = {0, 0, 0, 0};

    for (int k0 = 0; k0 < Sq; k0 += 64) {
        // ---- stage K rows + V transposed ----
        {
            const int r = t >> 2, c = (t & 3) * 16;
            const ushort* src = kb + (rowbase + k0 + r) * Hd + colbase + c;
            int4 ka = *(const int4*)(src);
            int4 kc = *(const int4*)(src + 8);
            *(int4*)&Ks[r][c]     = ka;
            *(int4*)&Ks[r][c + 8] = kc;

            const int kp = t & 31, db = (t >> 5) * 8;
            union { int4 v; ushort u[8]; } v0, v1;
            v0.v = *(const int4*)(vb + (rowbase + k0 + 2 * kp)     * Hd + colbase + db);
            v1.v = *(const int4*)(vb + (rowbase + k0 + 2 * kp + 1) * Hd + colbase + db);
#pragma unroll
            for (int j = 0; j < 8; ++j)
                *(unsigned*)&Vt[db + j][2 * kp] = (unsigned)v0.u[j] | ((unsigned)v1.u[j] << 16);
        }
        __syncthreads();

        // ---- mask prefetch (post-softmax multiplicative mask, shared over heads) ----
        float mv[4][4];
        const int qrow0 = qt * 64 + wave * 16 + quad * 4;
#pragma unroll
        for (int nt = 0; nt < 4; ++nt) {
            const int kcol = k0 + nt * 16 + l15;
#pragma unroll
            for (int r = 0; r < 4; ++r)
                mv[nt][r] = mask[((size_t)b * Sq + (qrow0 + r)) * Sq + kcol];
        }

        // ---- S = Q K^T / 8 ----
        f32x4 s[4] = {{0,0,0,0},{0,0,0,0},{0,0,0,0},{0,0,0,0}};
#pragma unroll
        for (int nt = 0; nt < 4; ++nt) {
            bf16x8 b0 = *(const bf16x8*)&Ks[nt * 16 + l15][quad * 8];
            bf16x8 b1 = *(const bf16x8*)&Ks[nt * 16 + l15][32 + quad * 8];
            s[nt] = __builtin_amdgcn_mfma_f32_16x16x32_bf16(qf0, b0, s[nt], 0, 0, 0);
            s[nt] = __builtin_amdgcn_mfma_f32_16x16x32_bf16(qf1, b1, s[nt], 0, 0, 0);
        }
#pragma unroll
        for (int nt = 0; nt < 4; ++nt)
#pragma unroll
            for (int r = 0; r < 4; ++r) s[nt][r] *= 0.125f;

        // ---- online softmax (rows = quad*4 + r; cols spread across lanes 0-15 of group) ----
        float mnew[4], alpha[4], rs[4];
#pragma unroll
        for (int r = 0; r < 4; ++r) {
            float mx = fmaxf(fmaxf(s[0][r], s[1][r]), fmaxf(s[2][r], s[3][r]));
#pragma unroll
            for (int off = 1; off < 16; off <<= 1) mx = fmaxf(mx, __shfl_xor(mx, off));
            mnew[r]  = fmaxf(m_i[r], mx);
            alpha[r] = __expf(m_i[r] - mnew[r]);
            m_i[r]   = mnew[r];
        }
        float p[4][4];
#pragma unroll
        for (int r = 0; r < 4; ++r) rs[r] = 0.0f;
#pragma unroll
        for (int nt = 0; nt < 4; ++nt)
#pragma unroll
            for (int r = 0; r < 4; ++r) {
                p[nt][r] = __expf(s[nt][r] - mnew[r]);
                rs[r] += p[nt][r];
            }
#pragma unroll
        for (int r = 0; r < 4; ++r) {
#pragma unroll
            for (int off = 1; off < 16; off <<= 1) rs[r] += __shfl_xor(rs[r], off);
            l_i[r] = l_i[r] * alpha[r] + rs[r];
        }
        // rescale O
#pragma unroll
        for (int dt = 0; dt < 4; ++dt)
#pragma unroll
            for (int r = 0; r < 4; ++r) o[dt][r] *= alpha[r];

        // ---- masked P -> LDS (transpose C-layout -> A-layout), bf16 ----
#pragma unroll
        for (int nt = 0; nt < 4; ++nt)
#pragma unroll
            for (int r = 0; r < 4; ++r)
                *(ushort*)&Pt[wave][quad * 4 + r][nt * 16 + l15] = f2bf(p[nt][r] * mv[nt][r]);

        // ---- O += P_masked @ V ----
#pragma unroll
        for (int st = 0; st < 2; ++st) {
            bf16x8 pf = *(const bf16x8*)&Pt[wave][l15][st * 32 + quad * 8];
#pragma unroll
            for (int dt = 0; dt < 4; ++dt) {
                bf16x8 vf = *(const bf16x8*)&Vt[dt * 16 + l15][st * 32 + quad * 8];
                o[dt] = __builtin_amdgcn_mfma_f32_16x16x32_bf16(pf, vf, o[dt], 0, 0, 0);
            }
        }
        __syncthreads();
    }

    // ---- epilogue: O / l  ->  ctx fp32 ----
#pragma unroll
    for (int r = 0; r < 4; ++r) {
        const float inv = 1.0f / l_i[r];
        const size_t row = rowbase + qt * 64 + wave * 16 + quad * 4 + r;
#pragma unroll
        for (int dt = 0; dt < 4; ++dt)
            ctx[row * Hd + colbase + dt * 16 + l15] = o[dt][r] * inv;
    }
}

// ---------------- fused residual + layernorm: out = LN(a + b)*g + be ----------------
__global__ __launch_bounds__(256) void ln_kernel(const float* __restrict__ a,
                                                 const float* __restrict__ bres,
                                                 const float* __restrict__ g,
                                                 const float* __restrict__ be,
                                                 float* __restrict__ out) {
    const int row = blockIdx.x;
    const int t   = threadIdx.x;
    const float* pa = a + (size_t)row * Hd;
    const float* pb = bres + (size_t)row * Hd;
    __shared__ float red[4];
    float v[3];
#pragma unroll
    for (int i = 0; i < 3; ++i) v[i] = pa[t + i * 256] + pb[t + i * 256];

    float s = v[0] + v[1] + v[2];
#pragma unroll
    for (int off = 32; off > 0; off >>= 1) s += __shfl_xor(s, off);
    if ((t & 63) == 0) red[t >> 6] = s;
    __syncthreads();
    const float mu = (red[0] + red[1] + red[2] + red[3]) * (1.0f / Hd);
    __syncthreads();

    float sq = 0.0f;
#pragma unroll
    for (int i = 0; i < 3; ++i) {
        v[i] -= mu;
        sq = fmaf(v[i], v[i], sq);
    }
#pragma unroll
    for (int off = 32; off > 0; off >>= 1) sq += __shfl_xor(sq, off);
    if ((t & 63) == 0) red[t >> 6] = sq;
    __syncthreads();
    const float var = (red[0] + red[1] + red[2] + red[3]) * (1.0f / Hd);
    const float rs  = rsqrtf(var + 1e-5f);
#pragma unroll
    for (int i = 0; i < 3; ++i) {
        const int idx = t + i * 256;
        out[(size_t)row * Hd + idx] = v[i] * rs * g[idx] + be[idx];
    }
}

extern "C" void kernel_launch(void* const* d_in, const int* in_sizes, int n_in,
                              void* d_out, int out_size, void* d_ws, size_t ws_size,
                              hipStream_t stream) {
    const float* x1    = (const float*)d_in[0];
    const float* wmask = (const float*)d_in[1];
    const float* Wq    = (const float*)d_in[2];
    const float* bq    = (const float*)d_in[3];
    const float* Wk    = (const float*)d_in[4];
    const float* bk    = (const float*)d_in[5];
    const float* Wv    = (const float*)d_in[6];
    const float* bv    = (const float*)d_in[7];
    const float* g1    = (const float*)d_in[8];
    const float* be1   = (const float*)d_in[9];
    const float* g2    = (const float*)d_in[10];
    const float* be2   = (const float*)d_in[11];
    const float* W1    = (const float*)d_in[12];
    const float* b1    = (const float*)d_in[13];
    const float* W2    = (const float*)d_in[14];
    const float* b2    = (const float*)d_in[15];
    float* out = (float*)d_out;
    float* ws  = (float*)d_ws;

    const size_t NT = (size_t)Bsz * Sq * Hd;    // 6291456
    float* qm   = ws;                           // [8192,768] fp32
    float* km   = ws + NT;
    float* vm   = ws + 2 * NT;
    float* ctx  = ws + 3 * NT;
    float* hbF  = ws + 4 * NT;                  // [8192,1536] fp32 (FFN hidden, used later)
    // bf16 copies live inside the (not yet used) FFN-hidden region: 3*NT ushorts <= 2*NT floats
    ushort* qb  = (ushort*)hbF;
    ushort* kb  = qb + NT;
    ushort* vb  = kb + NT;
    float* xb   = km;                           // reuse after attention
    float* ffb  = vm;                           // reuse after attention

    const int M = Bsz * Sq;                     // 8192
    dim3 blk(256);

    gemm_bias<false><<<dim3(Hd / 64, M / 64), blk, 0, stream>>>(x1, Wq, bq, qm, M, Hd, Hd);
    gemm_bias<false><<<dim3(Hd / 64, M / 64), blk, 0, stream>>>(x1, Wk, bk, km, M, Hd, Hd);
    gemm_bias<false><<<dim3(Hd / 64, M / 64), blk, 0, stream>>>(x1, Wv, bv, vm, M, Hd, Hd);

    const int n4 = (int)(NT / 4);
    cvt_bf16<<<dim3(n4 / 256), blk, 0, stream>>>(qm, qb, n4);
    cvt_bf16<<<dim3(n4 / 256), blk, 0, stream>>>(km, kb, n4);
    cvt_bf16<<<dim3(n4 / 256), blk, 0, stream>>>(vm, vb, n4);

    attn_mfma<<<dim3(Bsz * NHd * (Sq / 64)), blk, 0, stream>>>(qb, kb, vb, wmask, ctx);

    ln_kernel<<<dim3(M), blk, 0, stream>>>(ctx, qm, g1, be1, xb);

    gemm_bias<true ><<<dim3((2 * Hd) / 64, M / 64), blk, 0, stream>>>(xb, W1, b1, hbF, M, 2 * Hd, Hd);
    gemm_bias<false><<<dim3(Hd / 64, M / 64), blk, 0, stream>>>(hbF, W2, b2, ffb, M, Hd, 2 * Hd);

    ln_kernel<<<dim3(M), blk, 0, stream>>>(xb, ffb, g2, be2, out);
}

// Round 3
// 402.166 us; speedup vs baseline: 8.4101x; 3.1041x over previous
//
#include <hip/hip_runtime.h>
#include <math.h>

#define Bsz 8
#define Sq  1024
#define Hd  768
#define NHd 12
#define DHd 64
#define QS  2304   // packed qkv row stride (ushorts)

typedef __attribute__((ext_vector_type(8))) short bf16x8;
typedef __attribute__((ext_vector_type(4))) float f32x4;

__device__ __forceinline__ ushort f2bf(float f) {
    unsigned u = __float_as_uint(f);
    u += 0x7fffu + ((u >> 16) & 1u);     // RNE
    return (ushort)(u >> 16);
}
__device__ __forceinline__ float bf2f(ushort u) {
    return __uint_as_float(((unsigned)u) << 16);
}
__device__ __forceinline__ void load_lds16(const ushort* g, ushort* l) {
    __builtin_amdgcn_global_load_lds((const __attribute__((address_space(1))) void*)g,
                                     (__attribute__((address_space(3))) void*)l, 16, 0, 0);
}

// ---------------- fp32 -> bf16 conversion (4 elems/thread) ----------------
__global__ __launch_bounds__(256) void cvt_bf16(const float* __restrict__ a,
                                                ushort* __restrict__ o, int n4) {
    int i = blockIdx.x * 256 + threadIdx.x;
    if (i < n4) {
        float4 f = ((const float4*)a)[i];
        ushort4 u;
        u.x = f2bf(f.x); u.y = f2bf(f.y); u.z = f2bf(f.z); u.w = f2bf(f.w);
        ((ushort4*)o)[i] = u;
    }
}

// ---------------- transpose + convert: in[K,N] fp32 -> out[N,K] bf16 ----------------
__global__ __launch_bounds__(256) void transpose_cvt(const float* __restrict__ in,
                                                     ushort* __restrict__ out,
                                                     int K, int N) {
    __shared__ float tile[32][33];
    const int n0 = blockIdx.x * 32, k0 = blockIdx.y * 32;
    const int tx = threadIdx.x & 31, ty = threadIdx.x >> 5;   // ty 0..7
#pragma unroll
    for (int i = ty; i < 32; i += 8)
        tile[i][tx] = in[(size_t)(k0 + i) * N + n0 + tx];
    __syncthreads();
#pragma unroll
    for (int i = ty; i < 32; i += 8)
        out[(size_t)(n0 + i) * K + k0 + tx] = f2bf(tile[tx][i]);
}

__global__ __launch_bounds__(256) void concat_bias(const float* __restrict__ bq,
                                                   const float* __restrict__ bk,
                                                   const float* __restrict__ bv,
                                                   float* __restrict__ o) {
    int i = blockIdx.x * 256 + threadIdx.x;
    if (i < 2304)
        o[i] = i < 768 ? bq[i] : (i < 1536 ? bk[i - 768] : bv[i - 1536]);
}

// ---------------- bf16 MFMA GEMM: C = A[M,K] @ BT[N,K]^T + bias ----------------
// 128x128 tile, BK=64, 256 thr = 4 waves (2x2), each wave 64x64 via 4x4 mfma 16x16x32.
// LDS XOR-swizzled in 16B granules; swizzle applied on global address side so
// global_load_lds (lane-contiguous LDS dest) works; ds_read_b128 -> 2-way conflicts (free).
template<bool RELU, bool OUT_BF16>
__global__ __launch_bounds__(256) void gemm_mfma(const ushort* __restrict__ A,
                                                 const ushort* __restrict__ BT,
                                                 const float* __restrict__ bias,
                                                 void* __restrict__ Cout,
                                                 int M, int N, int K) {
    const int bm = blockIdx.y * 128;
    const int bn = blockIdx.x * 128;
    const int t  = threadIdx.x;
    const int wave = t >> 6, lane = t & 63;
    const int l15 = lane & 15, quad = lane >> 4;
    const int wm = (wave >> 1) * 64, wn = (wave & 1) * 64;

    __shared__ ushort As[128 * 64];
    __shared__ ushort Bs[128 * 64];

    f32x4 acc[4][4];
#pragma unroll
    for (int i = 0; i < 4; ++i)
#pragma unroll
        for (int j = 0; j < 4; ++j) acc[i][j] = (f32x4){0, 0, 0, 0};

    // per-thread staging granule (constant across K loop)
    const int g_row[4] = {(0 * 256 + t) >> 3, (1 * 256 + t) >> 3, (2 * 256 + t) >> 3, (3 * 256 + t) >> 3};
    const int g_pc     = t & 7;

    for (int k0 = 0; k0 < K; k0 += 64) {
#pragma unroll
        for (int it = 0; it < 4; ++it) {
            const int row = g_row[it];
            const int cb  = g_pc ^ (row & 7);
            load_lds16(A  + (size_t)(bm + row) * K + k0 + cb * 8,
                       As + (size_t)(it * 256 + wave * 64) * 8);
            load_lds16(BT + (size_t)(bn + row) * K + k0 + cb * 8,
                       Bs + (size_t)(it * 256 + wave * 64) * 8);
        }
        __syncthreads();
#pragma unroll
        for (int kk = 0; kk < 64; kk += 32) {
            bf16x8 af[4], bfr[4];
            const int cbk = (kk >> 3) + quad;
#pragma unroll
            for (int i = 0; i < 4; ++i) {
                const int rowA = wm + i * 16 + l15;
                af[i]  = *(const bf16x8*)(As + (size_t)(rowA * 8 + (cbk ^ (rowA & 7))) * 8);
                const int rowB = wn + i * 16 + l15;
                bfr[i] = *(const bf16x8*)(Bs + (size_t)(rowB * 8 + (cbk ^ (rowB & 7))) * 8);
            }
#pragma unroll
            for (int i = 0; i < 4; ++i)
#pragma unroll
                for (int j = 0; j < 4; ++j)
                    acc[i][j] = __builtin_amdgcn_mfma_f32_16x16x32_bf16(af[i], bfr[j], acc[i][j], 0, 0, 0);
        }
        __syncthreads();
    }

#pragma unroll
    for (int i = 0; i < 4; ++i) {
#pragma unroll
        for (int r = 0; r < 4; ++r) {
            const int m = bm + wm + i * 16 + quad * 4 + r;
#pragma unroll
            for (int j = 0; j < 4; ++j) {
                const int n = bn + wn + j * 16 + l15;
                float v = acc[i][j][r] + bias[n];
                if (RELU) v = fmaxf(v, 0.0f);
                if (OUT_BF16) ((ushort*)Cout)[(size_t)m * N + n] = f2bf(v);
                else          ((float*)Cout)[(size_t)m * N + n] = v;
            }
        }
    }
}

// ---------------- MFMA flash attention (packed qkv input, stride QS) ----------------
__global__ __launch_bounds__(256) void attn_mfma(const ushort* __restrict__ qkv,
                                                 const float* __restrict__ mask,
                                                 float* __restrict__ ctx) {
    const int nqt  = Sq / 64;                 // 16
    const int bh   = blockIdx.x / nqt;
    const int qt   = blockIdx.x % nqt;
    const int b    = bh / NHd;
    const int h    = bh % NHd;
    const int t    = threadIdx.x;
    const int wave = t >> 6;
    const int lane = t & 63;
    const int l15  = lane & 15;
    const int quad = lane >> 4;

    __shared__ ushort Qs[64][72];
    __shared__ ushort Ks[64][72];
    __shared__ ushort Vt[DHd][72];
    __shared__ ushort Pt[4][16][72];

    const size_t rowbase = (size_t)b * Sq;
    const size_t colbase = (size_t)h * DHd;

    {
        const int r = t >> 2, c = (t & 3) * 16;
        const ushort* src = qkv + (rowbase + qt * 64 + r) * QS + colbase + c;
        *(int4*)&Qs[r][c]     = *(const int4*)(src);
        *(int4*)&Qs[r][c + 8] = *(const int4*)(src + 8);
    }
    __syncthreads();

    bf16x8 qf0 = *(const bf16x8*)&Qs[wave * 16 + l15][quad * 8];
    bf16x8 qf1 = *(const bf16x8*)&Qs[wave * 16 + l15][32 + quad * 8];

    f32x4 o[4] = {{0,0,0,0},{0,0,0,0},{0,0,0,0},{0,0,0,0}};
    float m_i[4] = {-INFINITY, -INFINITY, -INFINITY, -INFINITY};
    float l_i[4] = {0, 0, 0, 0};

    for (int k0 = 0; k0 < Sq; k0 += 64) {
        {
            const int r = t >> 2, c = (t & 3) * 16;
            const ushort* src = qkv + (rowbase + k0 + r) * QS + 768 + colbase + c;
            int4 ka = *(const int4*)(src);
            int4 kc = *(const int4*)(src + 8);
            *(int4*)&Ks[r][c]     = ka;
            *(int4*)&Ks[r][c + 8] = kc;

            const int kp = t & 31, db = (t >> 5) * 8;
            union { int4 v; ushort u[8]; } v0, v1;
            v0.v = *(const int4*)(qkv + (rowbase + k0 + 2 * kp)     * QS + 1536 + colbase + db);
            v1.v = *(const int4*)(qkv + (rowbase + k0 + 2 * kp + 1) * QS + 1536 + colbase + db);
#pragma unroll
            for (int j = 0; j < 8; ++j)
                *(unsigned*)&Vt[db + j][2 * kp] = (unsigned)v0.u[j] | ((unsigned)v1.u[j] << 16);
        }
        __syncthreads();

        float mv[4][4];
        const int qrow0 = qt * 64 + wave * 16 + quad * 4;
#pragma unroll
        for (int nt = 0; nt < 4; ++nt) {
            const int kcol = k0 + nt * 16 + l15;
#pragma unroll
            for (int r = 0; r < 4; ++r)
                mv[nt][r] = mask[((size_t)b * Sq + (qrow0 + r)) * Sq + kcol];
        }

        f32x4 s[4] = {{0,0,0,0},{0,0,0,0},{0,0,0,0},{0,0,0,0}};
#pragma unroll
        for (int nt = 0; nt < 4; ++nt) {
            bf16x8 b0 = *(const bf16x8*)&Ks[nt * 16 + l15][quad * 8];
            bf16x8 b1 = *(const bf16x8*)&Ks[nt * 16 + l15][32 + quad * 8];
            s[nt] = __builtin_amdgcn_mfma_f32_16x16x32_bf16(qf0, b0, s[nt], 0, 0, 0);
            s[nt] = __builtin_amdgcn_mfma_f32_16x16x32_bf16(qf1, b1, s[nt], 0, 0, 0);
        }
#pragma unroll
        for (int nt = 0; nt < 4; ++nt)
#pragma unroll
            for (int r = 0; r < 4; ++r) s[nt][r] *= 0.125f;

        float mnew[4], alpha[4], rs[4];
#pragma unroll
        for (int r = 0; r < 4; ++r) {
            float mx = fmaxf(fmaxf(s[0][r], s[1][r]), fmaxf(s[2][r], s[3][r]));
#pragma unroll
            for (int off = 1; off < 16; off <<= 1) mx = fmaxf(mx, __shfl_xor(mx, off));
            mnew[r]  = fmaxf(m_i[r], mx);
            alpha[r] = __expf(m_i[r] - mnew[r]);
            m_i[r]   = mnew[r];
        }
        float p[4][4];
#pragma unroll
        for (int r = 0; r < 4; ++r) rs[r] = 0.0f;
#pragma unroll
        for (int nt = 0; nt < 4; ++nt)
#pragma unroll
            for (int r = 0; r < 4; ++r) {
                p[nt][r] = __expf(s[nt][r] - mnew[r]);
                rs[r] += p[nt][r];
            }
#pragma unroll
        for (int r = 0; r < 4; ++r) {
#pragma unroll
            for (int off = 1; off < 16; off <<= 1) rs[r] += __shfl_xor(rs[r], off);
            l_i[r] = l_i[r] * alpha[r] + rs[r];
        }
#pragma unroll
        for (int dt = 0; dt < 4; ++dt)
#pragma unroll
            for (int r = 0; r < 4; ++r) o[dt][r] *= alpha[r];

#pragma unroll
        for (int nt = 0; nt < 4; ++nt)
#pragma unroll
            for (int r = 0; r < 4; ++r)
                *(ushort*)&Pt[wave][quad * 4 + r][nt * 16 + l15] = f2bf(p[nt][r] * mv[nt][r]);

#pragma unroll
        for (int st = 0; st < 2; ++st) {
            bf16x8 pf = *(const bf16x8*)&Pt[wave][l15][st * 32 + quad * 8];
#pragma unroll
            for (int dt = 0; dt < 4; ++dt) {
                bf16x8 vf = *(const bf16x8*)&Vt[dt * 16 + l15][st * 32 + quad * 8];
                o[dt] = __builtin_amdgcn_mfma_f32_16x16x32_bf16(pf, vf, o[dt], 0, 0, 0);
            }
        }
        __syncthreads();
    }

#pragma unroll
    for (int r = 0; r < 4; ++r) {
        const float inv = 1.0f / l_i[r];
        const size_t row = rowbase + qt * 64 + wave * 16 + quad * 4 + r;
#pragma unroll
        for (int dt = 0; dt < 4; ++dt)
            ctx[row * Hd + colbase + dt * 16 + l15] = o[dt][r] * inv;
    }
}

// ---------------- fused residual + layernorm ----------------
// out = LN(a + res)*g + be ; res may be bf16 w/ arbitrary row stride; optional bf16 copy out.
template<bool RES_BF16, bool EMIT_BF16>
__global__ __launch_bounds__(256) void ln_fused(const float* __restrict__ a,
                                                const void* __restrict__ res, int res_stride,
                                                const float* __restrict__ g,
                                                const float* __restrict__ be,
                                                float* __restrict__ outf,
                                                ushort* __restrict__ outb) {
    const int row = blockIdx.x;
    const int t   = threadIdx.x;
    const float* pa = a + (size_t)row * Hd;
    __shared__ float red[4];
    float v[3];
#pragma unroll
    for (int i = 0; i < 3; ++i) {
        const int idx = t + i * 256;
        float rv;
        if (RES_BF16) rv = bf2f(((const ushort*)res)[(size_t)row * res_stride + idx]);
        else          rv = ((const float*)res)[(size_t)row * res_stride + idx];
        v[i] = pa[idx] + rv;
    }

    float s = v[0] + v[1] + v[2];
#pragma unroll
    for (int off = 32; off > 0; off >>= 1) s += __shfl_xor(s, off);
    if ((t & 63) == 0) red[t >> 6] = s;
    __syncthreads();
    const float mu = (red[0] + red[1] + red[2] + red[3]) * (1.0f / Hd);
    __syncthreads();

    float sq = 0.0f;
#pragma unroll
    for (int i = 0; i < 3; ++i) {
        v[i] -= mu;
        sq = fmaf(v[i], v[i], sq);
    }
#pragma unroll
    for (int off = 32; off > 0; off >>= 1) sq += __shfl_xor(sq, off);
    if ((t & 63) == 0) red[t >> 6] = sq;
    __syncthreads();
    const float var = (red[0] + red[1] + red[2] + red[3]) * (1.0f / Hd);
    const float rs  = rsqrtf(var + 1e-5f);
#pragma unroll
    for (int i = 0; i < 3; ++i) {
        const int idx = t + i * 256;
        const float o = v[i] * rs * g[idx] + be[idx];
        outf[(size_t)row * Hd + idx] = o;
        if (EMIT_BF16) outb[(size_t)row * Hd + idx] = f2bf(o);
    }
}

extern "C" void kernel_launch(void* const* d_in, const int* in_sizes, int n_in,
                              void* d_out, int out_size, void* d_ws, size_t ws_size,
                              hipStream_t stream) {
    const float* x1    = (const float*)d_in[0];
    const float* wmask = (const float*)d_in[1];
    const float* Wq    = (const float*)d_in[2];
    const float* bq    = (const float*)d_in[3];
    const float* Wk    = (const float*)d_in[4];
    const float* bk    = (const float*)d_in[5];
    const float* Wv    = (const float*)d_in[6];
    const float* bv    = (const float*)d_in[7];
    const float* g1    = (const float*)d_in[8];
    const float* be1   = (const float*)d_in[9];
    const float* g2    = (const float*)d_in[10];
    const float* be2   = (const float*)d_in[11];
    const float* W1    = (const float*)d_in[12];
    const float* b1    = (const float*)d_in[13];
    const float* W2    = (const float*)d_in[14];
    const float* b2    = (const float*)d_in[15];
    float* out = (float*)d_out;

    const size_t NT = (size_t)Bsz * Sq * Hd;        // 6291456
    const int M = Bsz * Sq;                          // 8192

    char* p = (char*)d_ws;
    ushort* xb     = (ushort*)p;  p += NT * 2;                       // x1 bf16
    ushort* WqkvT  = (ushort*)p;  p += (size_t)2304 * 768 * 2;       // packed QKV weights^T
    ushort* W1T    = (ushort*)p;  p += (size_t)1536 * 768 * 2;
    ushort* W2T    = (ushort*)p;  p += (size_t)768 * 1536 * 2;
    float*  qkvbias= (float*)p;   p += 2304 * 4 + 256;
    ushort* qkvb   = (ushort*)p;  p += (size_t)M * QS * 2;           // qkv bf16 packed
    float*  ctxb   = (float*)p;   p += NT * 4;                       // ctx fp32 (later: ffb)
    float*  xf     = (float*)p;   p += NT * 4;                       // LN1 out fp32
    ushort* xbf    = (ushort*)p;  p += NT * 2;                       // LN1 out bf16
    ushort* hb     = qkvb;                                           // FFN hidden bf16 (reuse qkv)
    float*  ffb    = ctxb;                                           // FFN out fp32 (reuse ctx)

    dim3 blk(256);

    cvt_bf16<<<dim3((int)(NT / 4 / 256)), blk, 0, stream>>>(x1, xb, (int)(NT / 4));

    transpose_cvt<<<dim3(24, 24), blk, 0, stream>>>(Wq, WqkvT,                 768, 768);
    transpose_cvt<<<dim3(24, 24), blk, 0, stream>>>(Wk, WqkvT + 768 * 768,     768, 768);
    transpose_cvt<<<dim3(24, 24), blk, 0, stream>>>(Wv, WqkvT + 2 * 768 * 768, 768, 768);
    transpose_cvt<<<dim3(48, 24), blk, 0, stream>>>(W1, W1T, 768, 1536);
    transpose_cvt<<<dim3(24, 48), blk, 0, stream>>>(W2, W2T, 1536, 768);
    concat_bias<<<dim3(9), blk, 0, stream>>>(bq, bk, bv, qkvbias);

    // QKV fused GEMM: [8192,768] @ [768,2304] -> bf16 [8192,2304]
    gemm_mfma<false, true><<<dim3(2304 / 128, M / 128), blk, 0, stream>>>(
        xb, WqkvT, qkvbias, qkvb, M, 2304, 768);

    attn_mfma<<<dim3(Bsz * NHd * (Sq / 64)), blk, 0, stream>>>(qkvb, wmask, ctxb);

    // LN1: LN(ctx + q_mixed) -> fp32 + bf16
    ln_fused<true, true><<<dim3(M), blk, 0, stream>>>(ctxb, qkvb, QS, g1, be1, xf, xbf);

    // FFN1: [8192,768] @ [768,1536] + ReLU -> bf16
    gemm_mfma<true, true><<<dim3(1536 / 128, M / 128), blk, 0, stream>>>(
        xbf, W1T, b1, hb, M, 1536, 768);

    // FFN2: [8192,1536] @ [1536,768] -> fp32
    gemm_mfma<false, false><<<dim3(768 / 128, M / 128), blk, 0, stream>>>(
        hb, W2T, b2, ffb, M, 768, 1536);

    // LN2 -> out
    ln_fused<false, false><<<dim3(M), blk, 0, stream>>>(xf, ffb, Hd, g2, be2, out, nullptr);
}